// Round 1
// baseline (84.691 us; speedup 1.0000x reference)
//
#include <hip/hip_runtime.h>

// LIF forward: s[t] = (v >= 1) with v = decay*v + x[t], hard reset to 0 on spike.
// One thread owns 4 consecutive channels; v lives in registers across the T loop.
__global__ __launch_bounds__(256) void lif_fwd_kernel(
    const float4* __restrict__ x,      // [T, N/4]
    const float4* __restrict__ w4,     // [C/4]
    const float4* __restrict__ v0,     // [N/4]
    float4* __restrict__ out,          // [T, N/4]
    int n4, int c4, int T)
{
    int i = blockIdx.x * blockDim.x + threadIdx.x;
    if (i >= n4) return;

    // decay = 1 - sigmoid(w), per channel (once per thread, off the hot path)
    float4 wv = w4[i % c4];
    float4 dec;
    dec.x = 1.0f - 1.0f / (1.0f + expf(-wv.x));
    dec.y = 1.0f - 1.0f / (1.0f + expf(-wv.y));
    dec.z = 1.0f - 1.0f / (1.0f + expf(-wv.z));
    dec.w = 1.0f - 1.0f / (1.0f + expf(-wv.w));

    float4 v = v0[i];

    for (int t = 0; t < T; ++t) {
        float4 xt = x[(size_t)t * n4 + i];
        float4 s;
        // v = decay*v + x  (explicit round-per-op: match numpy mult-then-add, no FMA)
        v.x = __fadd_rn(__fmul_rn(dec.x, v.x), xt.x);
        v.y = __fadd_rn(__fmul_rn(dec.y, v.y), xt.y);
        v.z = __fadd_rn(__fmul_rn(dec.z, v.z), xt.z);
        v.w = __fadd_rn(__fmul_rn(dec.w, v.w), xt.w);
        // spike: h = v - 1.0 >= 0  <=>  v >= 1.0 ; hard reset to 0 on spike
        s.x = (v.x >= 1.0f) ? 1.0f : 0.0f;  v.x = (v.x >= 1.0f) ? 0.0f : v.x;
        s.y = (v.y >= 1.0f) ? 1.0f : 0.0f;  v.y = (v.y >= 1.0f) ? 0.0f : v.y;
        s.z = (v.z >= 1.0f) ? 1.0f : 0.0f;  v.z = (v.z >= 1.0f) ? 0.0f : v.z;
        s.w = (v.w >= 1.0f) ? 1.0f : 0.0f;  v.w = (v.w >= 1.0f) ? 0.0f : v.w;
        out[(size_t)t * n4 + i] = s;
    }
}

extern "C" void kernel_launch(void* const* d_in, const int* in_sizes, int n_in,
                              void* d_out, int out_size, void* d_ws, size_t ws_size,
                              hipStream_t stream) {
    const float* x      = (const float*)d_in[0];   // [T,B,S,C]
    const float* w      = (const float*)d_in[1];   // [C]
    const float* v_init = (const float*)d_in[2];   // [B,S,C]
    float* out = (float*)d_out;                    // [T,B,S,C]

    const int C = in_sizes[1];
    const int N = in_sizes[2];                     // B*S*C
    const int T = in_sizes[0] / N;
    const int n4 = N / 4;                          // C % 4 == 0 (C=512)
    const int c4 = C / 4;

    dim3 block(256);
    dim3 grid((n4 + block.x - 1) / block.x);
    lif_fwd_kernel<<<grid, block, 0, stream>>>(
        (const float4*)x, (const float4*)w, (const float4*)v_init,
        (float4*)out, n4, c4, T);
}